// Round 1
// baseline (21063.573 us; speedup 1.0000x reference)
//
#include <hip/hip_runtime.h>
#include <hip/hip_fp16.h>

// SpellerModel: 3-layer LSTM + attention decoder, T+1=201 sequential steps.
// Round 0: fp32 multi-kernel baseline (5 kernels/step), fp16 key/val copies
// for attention bandwidth. Ping-pong h buffers avoid in-place recurrence race.

#define BB 64
#define TT 200
#define SS 400
#define VV 34
#define EE 256
#define HH 512
#define KD 256
#define NSTEP 201

// ---------------------------------------------------------------- init ----
__global__ void k_init(const float* hx1, const float* cx1, const float* hx2,
                       const float* cx2, const float* hx3, const float* cx3,
                       const float* Wq, const float* bq, const float* Wv,
                       float* h1, float* c1, float* h2, float* c2,
                       float* h3, float* c3, float* ctx, float* lossacc,
                       float* WvT) {
  const int b = blockIdx.x, tid = threadIdx.x;
  __shared__ float hx[HH];
  for (int k = tid; k < HH; k += 256) {
    float v = hx1[k];
    hx[k] = v;
    h1[b * HH + k] = v;       c1[b * HH + k] = cx1[k];
    h2[b * HH + k] = hx2[k];  c2[b * HH + k] = cx2[k];
    h3[b * HH + k] = hx3[k];  c3[b * HH + k] = cx3[k];
  }
  __syncthreads();
  // initial ctx = hx1 @ Wq.T + bq (same row for every batch element)
  for (int c = tid; c < KD; c += 256) {
    float acc = bq[c];
    const float* wrow = Wq + (size_t)c * HH;
    for (int k = 0; k < HH; ++k) acc = fmaf(hx[k], wrow[k], acc);
    ctx[b * KD + c] = acc;
  }
  if (b == 0) {
    for (int i = tid; i < HH * VV; i += 256) {
      int h = i / VV, v = i % VV;
      WvT[i] = Wv[v * HH + h];
    }
    if (tid < BB) lossacc[tid] = 0.f;
  }
}

// ------------------------------------------------- key/val fp16 staging ---
// keyT16[b][k][s] = (half)key[b][s][k]   (transpose for coalesced energy)
// val16 [b][s][k] = (half)val[b][s][k]
__global__ void k_cvt(const float* key, const float* val, __half* keyT16,
                      __half* val16) {
  const int blk = blockIdx.x, tid = threadIdx.x;
  if (blk < 4096) {
    const int b = blk >> 6;
    const int rem = blk & 63;
    const int k0 = (rem >> 3) * 32, s0 = (rem & 7) * 50;
    __shared__ float ld[50][33];
    for (int idx = tid; idx < 1600; idx += 256) {
      int si = idx >> 5, ki = idx & 31;
      ld[si][ki] = key[(size_t)b * SS * KD + (size_t)(s0 + si) * KD + k0 + ki];
    }
    __syncthreads();
    for (int idx = tid; idx < 1600; idx += 256) {
      int ki = idx / 50, si = idx % 50;
      keyT16[(size_t)b * KD * SS + (size_t)(k0 + ki) * SS + s0 + si] =
          __float2half(ld[si][ki]);
    }
  } else {
    const int base = (blk - 4096) * 3200;
    for (int j = 0; j < 13; ++j) {
      int i = base + tid + j * 256;
      if (i < BB * SS * KD) val16[i] = __float2half(val[i]);
    }
  }
}

// ------------------------------------------------------------- LSTM ------
// grid 512 = bh(2 batch halves) x jw(256 hidden-unit pairs). K = 1024
// (x-part 512 + recurrent h 512). Each WG: 32 rows x 8 gate cols.
__global__ __launch_bounds__(256) void k_lstm(
    int t, int isL1, const float* xsrc, const float* embedding,
    const int* target, const float* h_in, float* h_out, float* c_st,
    const float* Wih, const float* Whh, const float* bih, const float* bhh) {
  const int tid = threadIdx.x;
  const int jw = blockIdx.x & 255;
  const int bh = blockIdx.x >> 8;
  const int j0 = jw * 2;
  __shared__ float actlds[32][132];
  __shared__ float wlds[8][132];

  const int sr = tid >> 3;          // staging/compute row 0..31
  const int skq = tid & 7;
  const int rg = bh * 32 + sr;
  int y = 0;
  if (isL1) y = (t == 0) ? 0 : target[(t - 1) * BB + rg];

  const int wc = tid >> 5;          // W staging col 0..7
  const int wk = (tid & 31) * 4;
  const int wgc = (wc >> 1) * 512 + j0 + (wc & 1);

  const int cc = tid & 7;           // compute col 0..7

  float accT = 0.f;
  for (int chunk = 0; chunk < 8; ++chunk) {
    const int kbase = chunk * 128;
#pragma unroll
    for (int i = 0; i < 4; ++i) {
      const int kl = skq * 16 + i * 4;
      const int kg = kbase + kl;
      float4 v;
      if (isL1) {
        if (kg < 256)
          v = *(const float4*)&embedding[(size_t)y * EE + kg];
        else if (kg < 512)
          v = *(const float4*)&xsrc[(size_t)rg * KD + (kg - 256)];
        else
          v = *(const float4*)&h_in[(size_t)rg * HH + (kg - 512)];
      } else {
        if (kg < 512)
          v = *(const float4*)&xsrc[(size_t)rg * HH + kg];
        else
          v = *(const float4*)&h_in[(size_t)rg * HH + (kg - 512)];
      }
      *(float4*)&actlds[sr][kl] = v;
    }
    {
      const int kg = kbase + wk;
      float4 wv;
      if (kg < 512)
        wv = *(const float4*)&Wih[(size_t)wgc * HH + kg];
      else
        wv = *(const float4*)&Whh[(size_t)wgc * HH + (kg - 512)];
      *(float4*)&wlds[wc][wk] = wv;
    }
    __syncthreads();
    float acc = 0.f;
#pragma unroll 8
    for (int k4 = 0; k4 < 32; ++k4) {
      const float4 x4 = *(const float4*)&actlds[sr][k4 * 4];
      const float4 w4 = *(const float4*)&wlds[cc][k4 * 4];
      acc = fmaf(x4.x, w4.x, acc);
      acc = fmaf(x4.y, w4.y, acc);
      acc = fmaf(x4.z, w4.z, acc);
      acc = fmaf(x4.w, w4.w, acc);
    }
    accT += acc;
    __syncthreads();
  }
  // gates -> LDS (reuse actlds), then pointwise LSTM cell
  float* gbuf = &actlds[0][0];      // [8][32]
  gbuf[cc * 32 + sr] = accT;
  __syncthreads();
  if (tid < 64) {
    const int jl = tid & 1, r = tid >> 1;
    const int rgg = bh * 32 + r;
    const int j = j0 + jl;
    float gi = gbuf[(0 + jl) * 32 + r] + bih[j] + bhh[j];
    float gf = gbuf[(2 + jl) * 32 + r] + bih[512 + j] + bhh[512 + j];
    float gg = gbuf[(4 + jl) * 32 + r] + bih[1024 + j] + bhh[1024 + j];
    float go = gbuf[(6 + jl) * 32 + r] + bih[1536 + j] + bhh[1536 + j];
    float cp = c_st[(size_t)rgg * HH + j];
    float si = 1.f / (1.f + expf(-gi));
    float sf = 1.f / (1.f + expf(-gf));
    float so = 1.f / (1.f + expf(-go));
    float cn = sf * cp + si * tanhf(gg);
    float hn = so * tanhf(cn);
    c_st[(size_t)rgg * HH + j] = cn;
    h_out[(size_t)rgg * HH + j] = hn;
  }
}

// ------------------------------------------------------------- q = h3@Wq.T
__global__ __launch_bounds__(256) void k_q(const float* h3, const float* Wq,
                                           const float* bq, float* q) {
  const int tid = threadIdx.x;
  const int cw = blockIdx.x & 31;
  const int bh = blockIdx.x >> 5;
  __shared__ float actlds[32][132];
  __shared__ float wlds[8][132];
  const int sr = tid >> 3, skq = tid & 7;
  const int rg = bh * 32 + sr;
  const int wc = tid >> 5, wk = (tid & 31) * 4;
  const int cc = tid & 7;
  float accT = 0.f;
  for (int chunk = 0; chunk < 4; ++chunk) {
    const int kbase = chunk * 128;
#pragma unroll
    for (int i = 0; i < 4; ++i) {
      const int kl = skq * 16 + i * 4;
      *(float4*)&actlds[sr][kl] =
          *(const float4*)&h3[(size_t)rg * HH + kbase + kl];
    }
    *(float4*)&wlds[wc][wk] =
        *(const float4*)&Wq[(size_t)(cw * 8 + wc) * HH + kbase + wk];
    __syncthreads();
    float acc = 0.f;
#pragma unroll 8
    for (int k4 = 0; k4 < 32; ++k4) {
      const float4 x4 = *(const float4*)&actlds[sr][k4 * 4];
      const float4 w4 = *(const float4*)&wlds[cc][k4 * 4];
      acc = fmaf(x4.x, w4.x, acc);
      acc = fmaf(x4.y, w4.y, acc);
      acc = fmaf(x4.z, w4.z, acc);
      acc = fmaf(x4.w, w4.w, acc);
    }
    accT += acc;
    __syncthreads();
  }
  const int gc = cw * 8 + cc;
  q[(size_t)rg * KD + gc] = accT + bq[gc];
}

// ------------------------------------------- attention + logits + nll ----
__global__ __launch_bounds__(512) void k_attn(
    int t, const float* h3, const float* qbuf, const __half* keyT16,
    const __half* val16, const float* amask, const float* WvT,
    const float* bv, const int* target, const float* tmask, float* ctx,
    float* lossacc, float* dout) {
  const int b = blockIdx.x;
  const int tid = threadIdx.x;
  __shared__ float h3l[HH];
  __shared__ float ql[KD];
  __shared__ float an[SS];
  __shared__ float red[8];
  __shared__ float lbufp[4][VV];
  __shared__ float lbuf[VV];
  for (int k = tid; k < HH; k += 512) h3l[k] = h3[(size_t)b * HH + k];
  if (tid < KD) ql[tid] = qbuf[(size_t)b * KD + tid];
  __syncthreads();

  const int s = tid;
  float e = -1e30f;
  if (s < SS) {
    float acc = 0.f;
    const __half* kp = keyT16 + (size_t)b * KD * SS + s;
#pragma unroll 4
    for (int k = 0; k < KD; ++k)
      acc = fmaf(ql[k], __half2float(kp[(size_t)k * SS]), acc);
    e = acc;
  }
  // row max
  float m = e;
  for (int o = 32; o; o >>= 1) m = fmaxf(m, __shfl_xor(m, o));
  if ((tid & 63) == 0) red[tid >> 6] = m;
  __syncthreads();
  m = red[0];
#pragma unroll
  for (int i = 1; i < 8; ++i) m = fmaxf(m, red[i]);
  // softmax
  float p = (s < SS) ? expf(e - m) : 0.f;
  float z = p;
  for (int o = 32; o; o >>= 1) z += __shfl_xor(z, o);
  __syncthreads();
  if ((tid & 63) == 0) red[tid >> 6] = z;
  __syncthreads();
  z = 0.f;
#pragma unroll
  for (int i = 0; i < 8; ++i) z += red[i];
  const float attn = p / z;
  if (b == 0 && s < SS) dout[1 + (size_t)t * SS + s] = attn;
  // masked renormalize
  float am = (s < SS) ? attn * amask[(size_t)b * SS + s] : 0.f;
  float sa = fabsf(am);
  for (int o = 32; o; o >>= 1) sa += __shfl_xor(sa, o);
  __syncthreads();
  if ((tid & 63) == 0) red[tid >> 6] = sa;
  __syncthreads();
  sa = 0.f;
#pragma unroll
  for (int i = 0; i < 8; ++i) sa += red[i];
  if (s < SS) an[s] = am / fmaxf(sa, 1e-12f);
  __syncthreads();
  // ctx on threads 0..255, logits partials on 256..511
  if (tid < KD) {
    float acc = 0.f;
    const __half* vp = val16 + (size_t)b * SS * KD + tid;
#pragma unroll 4
    for (int ss = 0; ss < SS; ++ss)
      acc = fmaf(an[ss], __half2float(vp[(size_t)ss * KD]), acc);
    ctx[(size_t)b * KD + tid] = acc;
  } else if (t < TT) {
    const int lt = tid - 256;
    const int vv = lt & 63, hp = lt >> 6;
    if (vv < VV) {
      float acc = 0.f;
      for (int h = hp * 128; h < hp * 128 + 128; ++h)
        acc = fmaf(h3l[h], WvT[h * VV + vv], acc);
      lbufp[hp][vv] = acc;
    }
  }
  __syncthreads();
  if (t < TT) {
    if (tid < VV)
      lbuf[tid] = bv[tid] + lbufp[0][tid] + lbufp[1][tid] + lbufp[2][tid] +
                  lbufp[3][tid];
    __syncthreads();
    if (tid == 0) {
      float M2 = lbuf[0];
      for (int v = 1; v < VV; ++v) M2 = fmaxf(M2, lbuf[v]);
      float Z2 = 0.f;
      for (int v = 0; v < VV; ++v) Z2 += expf(lbuf[v] - M2);
      const int yy = target[t * BB + b];
      const float nll = -(lbuf[yy] - M2 - logf(Z2));
      lossacc[b] += tmask[t * BB + b] * nll;
    }
  }
}

// ------------------------------------------------------------- loss ------
__global__ void k_loss(const float* lossacc, float* dout) {
  const int tid = threadIdx.x;
  float v = (tid < BB) ? lossacc[tid] : 0.f;
  for (int o = 32; o; o >>= 1) v += __shfl_xor(v, o);
  if (tid == 0) dout[0] = v / (float)BB;
}

// ------------------------------------------------------------ launch -----
extern "C" void kernel_launch(void* const* d_in, const int* in_sizes, int n_in,
                              void* d_out, int out_size, void* d_ws,
                              size_t ws_size, hipStream_t stream) {
  const int* target = (const int*)d_in[0];
  const float* tmask = (const float*)d_in[1];
  const float* key = (const float*)d_in[2];
  const float* val = (const float*)d_in[3];
  const float* amask = (const float*)d_in[4];
  const float* emb = (const float*)d_in[5];
  const float* Wih1 = (const float*)d_in[6];
  const float* Whh1 = (const float*)d_in[7];
  const float* bih1 = (const float*)d_in[8];
  const float* bhh1 = (const float*)d_in[9];
  const float* Wih2 = (const float*)d_in[10];
  const float* Whh2 = (const float*)d_in[11];
  const float* bih2 = (const float*)d_in[12];
  const float* bhh2 = (const float*)d_in[13];
  const float* Wih3 = (const float*)d_in[14];
  const float* Whh3 = (const float*)d_in[15];
  const float* bih3 = (const float*)d_in[16];
  const float* bhh3 = (const float*)d_in[17];
  const float* Wq = (const float*)d_in[18];
  const float* bq = (const float*)d_in[19];
  const float* Wv = (const float*)d_in[20];
  const float* bv = (const float*)d_in[21];
  const float* hx1 = (const float*)d_in[22];
  const float* cx1 = (const float*)d_in[23];
  const float* hx2 = (const float*)d_in[24];
  const float* cx2 = (const float*)d_in[25];
  const float* hx3 = (const float*)d_in[26];
  const float* cx3 = (const float*)d_in[27];
  float* out = (float*)d_out;

  float* ws = (float*)d_ws;
  float* h1[2] = {ws + 0, ws + 32768};
  float* h2[2] = {ws + 65536, ws + 98304};
  float* h3[2] = {ws + 131072, ws + 163840};
  float* c1 = ws + 196608;
  float* c2 = ws + 229376;
  float* c3 = ws + 262144;
  float* ctx = ws + 294912;
  float* qb = ws + 311296;
  float* lossacc = ws + 327680;
  float* WvT = ws + 327744;  // 512*34
  __half* keyT16 = (__half*)((char*)d_ws + (2u << 20));
  __half* val16 = keyT16 + (size_t)BB * KD * SS;

  hipLaunchKernelGGL(k_init, dim3(64), dim3(256), 0, stream, hx1, cx1, hx2,
                     cx2, hx3, cx3, Wq, bq, Wv, h1[0], c1, h2[0], c2, h3[0],
                     c3, ctx, lossacc, WvT);
  hipLaunchKernelGGL(k_cvt, dim3(6144), dim3(256), 0, stream, key, val,
                     keyT16, val16);

  for (int t = 0; t < NSTEP; ++t) {
    const int cur = t & 1, nxt = cur ^ 1;
    hipLaunchKernelGGL(k_lstm, dim3(512), dim3(256), 0, stream, t, 1, ctx,
                       emb, target, h1[cur], h1[nxt], c1, Wih1, Whh1, bih1,
                       bhh1);
    hipLaunchKernelGGL(k_lstm, dim3(512), dim3(256), 0, stream, t, 0, h1[nxt],
                       emb, target, h2[cur], h2[nxt], c2, Wih2, Whh2, bih2,
                       bhh2);
    hipLaunchKernelGGL(k_lstm, dim3(512), dim3(256), 0, stream, t, 0, h2[nxt],
                       emb, target, h3[cur], h3[nxt], c3, Wih3, Whh3, bih3,
                       bhh3);
    hipLaunchKernelGGL(k_q, dim3(64), dim3(256), 0, stream, h3[nxt], Wq, bq,
                       qb);
    hipLaunchKernelGGL(k_attn, dim3(64), dim3(512), 0, stream, t, h3[nxt], qb,
                       keyT16, val16, amask, WvT, bv, target, tmask, ctx,
                       lossacc, out);
  }
  hipLaunchKernelGGL(k_loss, dim3(1), dim3(64), 0, stream, lossacc, out);
}